// Round 5
// baseline (288.325 us; speedup 1.0000x reference)
//
#include <hip/hip_runtime.h>

using u8  = unsigned char;
using u16 = unsigned short;
using u32 = unsigned int;
using s16x8 = __attribute__((ext_vector_type(8))) short;
using bf16x8 = __attribute__((ext_vector_type(8))) __bf16;
using f32x4 = __attribute__((ext_vector_type(4))) float;
using i32x4 = __attribute__((ext_vector_type(4))) int;
using i32x8 = __attribute__((ext_vector_type(8))) int;

__device__ inline u16 f2bf(float f) {
  u32 u = __float_as_uint(f);
  u = (u + 0x7FFFu + ((u >> 16) & 1u)) >> 16;
  return (u16)u;
}

// fp8 e4m3 (OCP) convert via HW pack instruction; take low byte
__device__ inline u8 f2fp8(float f) {
  return (u8)(__builtin_amdgcn_cvt_pk_fp8_f32(f, f, 0, false) & 0xFF);
}

__device__ inline f32x4 mfma16(s16x8 a, s16x8 b, f32x4 c) {
  return __builtin_amdgcn_mfma_f32_16x16x32_bf16(
      __builtin_bit_cast(bf16x8, a), __builtin_bit_cast(bf16x8, b), c, 0, 0, 0);
}

// MX fp8 MFMA, K=128, unit scales (e8m0 127 = 2^0): plain fp8 GEMM @2x bf16 rate
__device__ inline f32x4 mfma_fp8(i32x8 a, i32x8 b, f32x4 c) {
  return __builtin_amdgcn_mfma_scale_f32_16x16x128_f8f6f4(
      a, b, c, 0 /*A=fp8*/, 0 /*B=fp8*/, 0, 127, 0, 127);
}

// async global->LDS, 16B/lane; LDS dest = wave-uniform base + lane*16
__device__ inline void load_lds16(const void* g, void* l) {
  __builtin_amdgcn_global_load_lds(
      (const __attribute__((address_space(1))) void*)g,
      (__attribute__((address_space(3))) void*)l, 16, 0, 0);
}

// ---------------------------------------------------------------------------
__global__ __launch_bounds__(256) void cast_x12(
    const float* __restrict__ x1, const float* __restrict__ x2,
    u16* __restrict__ o1, u16* __restrict__ o2) {
  const float* in = blockIdx.y ? x2 : x1;
  u16* out = blockIdx.y ? o2 : o1;
  int i = (blockIdx.x * 256 + threadIdx.x) * 4;
  float4 f = *(const float4*)(in + i);
  ushort4 o;
  o.x = f2bf(f.x); o.y = f2bf(f.y); o.z = f2bf(f.z); o.w = f2bf(f.w);
  *(ushort4*)(out + i) = o;
}

// weights cast (y=0..2)
__global__ __launch_bounds__(256) void cast_w3z(
    const float* __restrict__ a, const float* __restrict__ b,
    const float* __restrict__ c, u16* __restrict__ oa, u16* __restrict__ ob,
    u16* __restrict__ oc) {
  const float* in = blockIdx.y == 0 ? a : (blockIdx.y == 1 ? b : c);
  u16* out = blockIdx.y == 0 ? oa : (blockIdx.y == 1 ? ob : oc);
  int i = (blockIdx.x * 256 + threadIdx.x) * 4;
  float4 f = *(const float4*)(in + i);
  ushort4 o;
  o.x = f2bf(f.x); o.y = f2bf(f.y); o.z = f2bf(f.z); o.w = f2bf(f.w);
  *(ushort4*)(out + i) = o;
}

// ---------------------------------------------------------------------------
// bf16 GEMM, C[m,n] = sum_k A[m,k]*B[n,k]  (operands K-contiguous).
// 128x128 tile, BK=64, 4 waves, XOR granule swizzle (0 bank conflicts).
// XCD-chunked block swizzle (nwg%8==0).
// EPI 0: q projection -> fp8 row-major (+bias)
// EPI 4: fused k/v: n0<512 -> kb fp8 (+bias); n0>=512 -> vT bf16 repack (+bias2)
// ---------------------------------------------------------------------------
template <int EPI>
__global__ __launch_bounds__(256) void gemm64(
    const u16* __restrict__ A, const u16* __restrict__ B,
    const u16* __restrict__ B2, void* __restrict__ C, void* __restrict__ C2,
    const float* __restrict__ bias, const float* __restrict__ bias2,
    int M, int N, int K, long sA, long sB, long sC) {
  const int bz = blockIdx.z;
  const int nwg = gridDim.x * gridDim.y;
  int flat = blockIdx.x + gridDim.x * blockIdx.y;
  flat = (flat & 7) * (nwg >> 3) + (flat >> 3);  // XCD-chunked remap
  const int m0 = (flat / gridDim.x) * 128;
  const int n0 = (flat % gridDim.x) * 128;
  const u16* Ab = A + (size_t)bz * sA;
  const u16* Bsel = (EPI == 4 && n0 >= 512) ? B2 : B;
  const int nb = (EPI == 4 && n0 >= 512) ? n0 - 512 : n0;
  const u16* Bb = Bsel + (size_t)bz * sB;
  const int tid = threadIdx.x;
  const int lane = tid & 63;
  const int wave = tid >> 6;
  const int wm = (wave >> 1) * 64;
  const int wn = (wave & 1) * 64;

  __shared__ u16 SM[128 * 64 * 2];
  u16* As = SM;
  u16* Bs = SM + 128 * 64;

  const int sr = lane >> 3;        // row within 8-row chunk
  const int gd = (lane & 7) ^ sr;  // swizzled source granule (16B units)
  const int ch0 = wave * 4;

  f32x4 acc[4][4];
#pragma unroll
  for (int i = 0; i < 4; ++i)
#pragma unroll
    for (int j = 0; j < 4; ++j) acc[i][j] = 0.0f;

  const int fr = lane & 15;
  const int fg = lane >> 4;  // 0..3

  for (int k0 = 0; k0 < K; k0 += 64) {
#pragma unroll
    for (int it = 0; it < 4; ++it) {
      const int ch = ch0 + it;
      const int row = ch * 8 + sr;
      load_lds16(Ab + (size_t)(m0 + row) * K + k0 + gd * 8, &As[ch * 512]);
      load_lds16(Bb + (size_t)(nb + row) * K + k0 + gd * 8, &Bs[ch * 512]);
    }
    __syncthreads();
#pragma unroll
    for (int s = 0; s < 2; ++s) {
      const int slot = ((s * 4 + fg) ^ (fr & 7)) * 8;
      s16x8 af[4], bfr[4];
#pragma unroll
      for (int i = 0; i < 4; ++i) {
        af[i]  = *(const s16x8*)&As[(wm + i * 16 + fr) * 64 + slot];
        bfr[i] = *(const s16x8*)&Bs[(wn + i * 16 + fr) * 64 + slot];
      }
#pragma unroll
      for (int mi = 0; mi < 4; ++mi)
#pragma unroll
        for (int ni = 0; ni < 4; ++ni)
          acc[mi][ni] = mfma16(af[mi], bfr[ni], acc[mi][ni]);
    }
    __syncthreads();
  }

  // C/D layout: col = lane&15, row = (lane>>4)*4 + i
  const int er = fg * 4;
  const int ec = fr;

  if (EPI == 0) {
    u8* Cb = (u8*)C;
#pragma unroll
    for (int mi = 0; mi < 4; ++mi)
#pragma unroll
      for (int ni = 0; ni < 4; ++ni) {
        const int col = n0 + wn + ni * 16 + ec;
        const float badd = bias[col];
#pragma unroll
        for (int i = 0; i < 4; ++i) {
          const int row = m0 + wm + mi * 16 + er + i;
          Cb[(size_t)row * N + col] = f2fp8(acc[mi][ni][i] + badd);
        }
      }
  } else {  // EPI == 4
    if (n0 < 512) {
      u8* Cb = (u8*)C;
#pragma unroll
      for (int mi = 0; mi < 4; ++mi)
#pragma unroll
        for (int ni = 0; ni < 4; ++ni) {
          const int col = n0 + wn + ni * 16 + ec;
          const float badd = bias[col];
#pragma unroll
          for (int i = 0; i < 4; ++i) {
            const int row = m0 + wm + mi * 16 + er + i;
            Cb[(size_t)row * 512 + col] = f2fp8(acc[mi][ni][i] + badd);
          }
        }
    } else {
      // v half: transpose via LDS repack, bf16 out. Tb[c][r], stride 136 u16.
      u16* Tb = SM;  // aliases dead staging
      const int batch = m0 >> 11;
      const int srow = m0 & 2047;
      u16* Cv = (u16*)C2 + (size_t)batch * (512 * 2048);
#pragma unroll
      for (int h = 0; h < 2; ++h) {
        if ((wn >> 6) == h) {
#pragma unroll
          for (int mi = 0; mi < 4; ++mi)
#pragma unroll
            for (int ni = 0; ni < 4; ++ni) {
              const int c = ni * 16 + ec;
              const float badd = bias2[n0 - 512 + wn + c];
#pragma unroll
              for (int i = 0; i < 4; ++i) {
                const int r = wm + mi * 16 + er + i;
                Tb[c * 136 + r] = f2bf(acc[mi][ni][i] + badd);
              }
            }
        }
        __syncthreads();
        const int d = tid >> 2;
        const int sc = (tid & 3) * 32;
        const int dglob = n0 - 512 + 64 * h + d;
#pragma unroll
        for (int j = 0; j < 4; ++j) {
          uint4 v = *(const uint4*)&Tb[d * 136 + sc + j * 8];
          *(uint4*)&Cv[(size_t)dglob * 2048 + srow + sc + j * 8] = v;
        }
        __syncthreads();
      }
    }
  }
}

// ---------------------------------------------------------------------------
// Fused attention v5. v4 post-mortem: no spill, but DS-port-bound — the
// 4m x 2n QK split read each K fragment 4x (128 KB/tile ds_read_b128),
// vs ~1790 cy/tile of MFMA. Changes:
//  (1) QK split 2m x 4n (wave = 32q x 16kv): K fragments read 2x -> 64
//      KB/tile, 8 ds_read_b128/wave. Qf grows 32->64 VGPR; budget
//      Qf 64 + Vr 32 + oacc 64(acc) + ~60 transients ~= 220 < 256 -> no
//      spill (tripwire: WRITE_SIZE must stay ~33 MB).
//  (2) P swizzle slot = g ^ ((r>>1)&7), pure-XOR: v4's (r&7) made fg-pair
//      rows (r, r+8) collide 4-way on the b16 P-writes. New form gives 8
//      distinct slots per store instr (2 lanes/bank = free) and keeps PV
//      b128 reads at the uniform minimum.
//  (3) s_setprio(1) around MFMA clusters.
// Pipeline per tile t (1 barrier): QK(Ks[t&1]) -> exp -> Ps[t&1] ->
//   barrier -> stageK(t+2 -> Ks[t&1]) -> PV(Ps[t&1], Vr) -> loadV(t+1).
// PV: pure d-split (64 d-cols/wave, V read once per block, regs only).
// ---------------------------------------------------------------------------
__global__ __launch_bounds__(512, 2) void attn_fused(
    const u8* __restrict__ q8, const u8* __restrict__ k8,
    const u16* __restrict__ vT, float* __restrict__ out) {
  const int batch = blockIdx.x;
  const int q0 = blockIdx.y * 64;
  const u8* qb = q8 + ((size_t)batch * 2048 + q0) * 512;
  const u8* kb = k8 + (size_t)batch * 2048 * 512;
  const u16* vb = vT + (size_t)batch * 512 * 2048;
  float* ob = out + ((size_t)batch * 2048 + q0) * 512;

  const int tid = threadIdx.x;
  const int lane = tid & 63;
  const int wave = tid >> 6;        // 0..7
  const int wm = (wave >> 2) * 32;  // QK q-row base (0/32)
  const int wn = (wave & 3) * 16;   // QK kv-col base (0/16/32/48)
  const int wd = wave * 64;         // PV d-col base
  const int sr = lane >> 3;
  const int gd = (lane & 7) ^ sr;   // staging swizzle (16B granules)
  const int fr = lane & 15;
  const int fg = lane >> 4;         // 0..3
  const int r7 = fr & 7;
  const int s0 = (2 * fg) ^ r7;     // LDS slot of k-lo granule (fp8 frags)
  const int s1 = s0 ^ 1;

  __shared__ u8 Ks[2][4][8192];   // dbuf x kc-chunk x (64 rows x 128B), swz
  __shared__ u16 Ps[2][64 * 64];  // dbuf P bf16, XOR-swizzled granules

  // ---- Q fragments -> registers: 2 mi x 4 kc (rows wm+mi*16+fr), 64 VGPRs
  i32x8 Qf[2][4];
#pragma unroll
  for (int mi = 0; mi < 2; ++mi)
#pragma unroll
    for (int kc = 0; kc < 4; ++kc) {
      const u8* p = qb + (size_t)(wm + mi * 16 + fr) * 512 + kc * 128 + fg * 32;
      i32x4 lo = *(const i32x4*)p;
      i32x4 hi = *(const i32x4*)(p + 16);
      i32x8 q;
      q[0] = lo[0]; q[1] = lo[1]; q[2] = lo[2]; q[3] = lo[3];
      q[4] = hi[0]; q[5] = hi[1]; q[6] = hi[2]; q[7] = hi[3];
      Qf[mi][kc] = q;
    }

  // 32KB K tile stage: 8 waves x 4 instrs
  auto stageK = [&](int kv0, int buf) {
#pragma unroll
    for (int it = 0; it < 4; ++it) {
      const int idx = wave * 4 + it;
      const int kc = idx >> 3, sub = idx & 7;
      load_lds16(kb + (size_t)(kv0 + sub * 8 + sr) * 512 + kc * 128 + gd * 16,
                 &Ks[buf][kc][sub * 1024]);
    }
  };
  // V frags for one tile -> 8 frags (ni4 x ks2) = 32 VGPR, d = wd + ni*16 + fr
  s16x8 Vr[8];
  auto loadV = [&](int kv0) {
#pragma unroll
    for (int ks = 0; ks < 2; ++ks)
#pragma unroll
      for (int ni = 0; ni < 4; ++ni)
        Vr[ks * 4 + ni] = *(const s16x8*)&vb[(size_t)(wd + ni * 16 + fr) * 2048 +
                                             kv0 + ks * 32 + fg * 8];
  };

  f32x4 oacc[4][4];
#pragma unroll
  for (int i = 0; i < 4; ++i)
#pragma unroll
    for (int j = 0; j < 4; ++j) oacc[i][j] = 0.0f;
  float l_reg[2][4] = {{0.0f, 0.0f, 0.0f, 0.0f}, {0.0f, 0.0f, 0.0f, 0.0f}};

  constexpr int NT = 32;

  auto tile = [&](int t, int psel) {
    // ---- QK^T: wave computes S[wm:wm+32)[wn:wn+16); one bK per kc, 2 mfma
    f32x4 sacc[2];
    sacc[0] = 0.0f; sacc[1] = 0.0f;
#pragma unroll
    for (int kc = 0; kc < 4; ++kc) {
      const u8* pb = &Ks[psel][kc][(wn + fr) * 128];
      i32x4 blo = *(const i32x4*)(pb + s0 * 16);
      i32x4 bhi = *(const i32x4*)(pb + s1 * 16);
      i32x8 bK;
      bK[0] = blo[0]; bK[1] = blo[1]; bK[2] = blo[2]; bK[3] = blo[3];
      bK[4] = bhi[0]; bK[5] = bhi[1]; bK[6] = bhi[2]; bK[7] = bhi[3];
      __builtin_amdgcn_s_setprio(1);
#pragma unroll
      for (int mi = 0; mi < 2; ++mi)
        sacc[mi] = mfma_fp8(Qf[mi][kc], bK, sacc[mi]);
      __builtin_amdgcn_s_setprio(0);
    }
    // ---- P = exp(S/D) -> Ps[psel], slot = g ^ ((r>>1)&7); l partials.
    // C/D frag: col = wn + (lane&15), row = wm + mi*16 + (lane>>4)*4 + i
    u16* Pd = &Ps[psel][0];
    const int g = (wn >> 3) + (fr >> 3);
    const int co = fr & 7;
#pragma unroll
    for (int mi = 0; mi < 2; ++mi)
#pragma unroll
      for (int i = 0; i < 4; ++i) {
        const int r = wm + mi * 16 + fg * 4 + i;
        const float p = __expf(sacc[mi][i] * (1.0f / 512.0f));
        l_reg[mi][i] += p;
        Pd[r * 64 + ((g ^ ((r >> 1) & 7)) << 3) + co] = f2bf(p);
      }
    __syncthreads();  // P visible; K(t+1) (issued tile t-1) staged
    // ---- prefetch K two tiles ahead into the buffer QK just released
    if (t + 2 < NT) stageK((t + 2) * 64, psel);
    // ---- PV: O[0:64)[wd..wd+64) += P * V (V from regs, loaded tile t-1)
#pragma unroll
    for (int ks = 0; ks < 2; ++ks) {
      s16x8 pa[4];
#pragma unroll
      for (int mi = 0; mi < 4; ++mi) {
        const int r = mi * 16 + fr;
        pa[mi] = *(const s16x8*)&Pd[r * 64 +
                                    (((ks * 4 + fg) ^ ((r >> 1) & 7)) << 3)];
      }
      __builtin_amdgcn_s_setprio(1);
#pragma unroll
      for (int ni = 0; ni < 4; ++ni)
#pragma unroll
        for (int mi = 0; mi < 4; ++mi)
          oacc[mi][ni] = mfma16(pa[mi], Vr[ks * 4 + ni], oacc[mi][ni]);
      __builtin_amdgcn_s_setprio(0);
    }
    // ---- V for next tile into the SAME regs (WAR after PV reads, in order)
    if (t + 1 < NT) loadV((t + 1) * 64);
  };

  // prologue: K0+V0, drain, then K1 in flight (drains at tile-0 barrier)
  stageK(0, 0);
  loadV(0);
  __syncthreads();
  stageK(64, 1);

  for (int tt = 0; tt < NT; tt += 2) {
    tile(tt, 0);
    tile(tt + 1, 1);
  }

  // ---- l: shuffle-reduce over 16 lanes (kv-cols), partials into Ps scratch
  float* lsc = (float*)&Ps[0][0];  // [4 n-slices][64 rows]
  __syncthreads();
#pragma unroll
  for (int mi = 0; mi < 2; ++mi)
#pragma unroll
    for (int i = 0; i < 4; ++i) {
      float rs = l_reg[mi][i];
      rs += __shfl_xor(rs, 1);
      rs += __shfl_xor(rs, 2);
      rs += __shfl_xor(rs, 4);
      rs += __shfl_xor(rs, 8);
      if (fr == 0) lsc[(wn >> 4) * 64 + wm + mi * 16 + fg * 4 + i] = rs;
    }
  __syncthreads();

  // ---- normalize + store (fp32)
#pragma unroll
  for (int mi = 0; mi < 4; ++mi)
#pragma unroll
    for (int i = 0; i < 4; ++i) {
      const int r = mi * 16 + fg * 4 + i;
      const float l = lsc[r] + lsc[64 + r] + lsc[128 + r] + lsc[192 + r];
      const float li = __builtin_amdgcn_rcpf(l);
#pragma unroll
      for (int ni = 0; ni < 4; ++ni)
        ob[(size_t)r * 512 + wd + ni * 16 + fr] = oacc[mi][ni][i] * li;
    }
}

// ---------------------------------------------------------------------------
extern "C" void kernel_launch(void* const* d_in, const int* in_sizes, int n_in,
                              void* d_out, int out_size, void* d_ws, size_t ws_size,
                              hipStream_t stream) {
  constexpr int B = 8, S = 2048, D = 512;
  constexpr size_t MS = (size_t)B * S;  // 16384 token rows

  const float* x1 = (const float*)d_in[0];
  const float* x2 = (const float*)d_in[1];
  const float* Wq = (const float*)d_in[2];
  const float* bq = (const float*)d_in[3];
  const float* Wk = (const float*)d_in[4];
  const float* bk = (const float*)d_in[5];
  const float* Wv = (const float*)d_in[6];
  const float* bv = (const float*)d_in[7];
  float* out = (float*)d_out;

  // workspace layout
  u16* x1b = (u16*)d_ws;              // MS*D bf16
  u16* x2b = x1b + MS * D;            // MS*D bf16
  u16* Wqb = x2b + MS * D;            // D*D bf16
  u16* Wkb = Wqb + (size_t)D * D;
  u16* Wvb = Wkb + (size_t)D * D;
  u16* vTb = Wvb + (size_t)D * D;     // MS*D bf16  [B][D][S]
  u16* Sc  = vTb + MS * D;            // (unused)
  float* lbuf = (float*)(Sc + (size_t)B * S * S);  // (unused)
  u8* qb8 = (u8*)(lbuf + MS);         // MS*D fp8
  u8* kb8 = qb8 + MS * D;             // MS*D fp8

  dim3 blk(256);

  cast_x12<<<dim3((MS * D) / 1024, 2), blk, 0, stream>>>(x1, x2, x1b, x2b);
  cast_w3z<<<dim3((D * D) / 1024, 3), blk, 0, stream>>>(
      Wq, Wk, Wv, Wqb, Wkb, Wvb);

  // q projection: M=16384, N=512, K=512 -> fp8
  gemm64<0><<<dim3(4, 128, 1), blk, 0, stream>>>(
      x1b, Wqb, nullptr, qb8, nullptr, bq, nullptr,
      16384, 512, 512, 0, 0, 0);

  // fused k+v projection: N=1024 (k half -> kb8 fp8, v half -> vTb bf16)
  gemm64<4><<<dim3(8, 128, 1), blk, 0, stream>>>(
      x2b, Wkb, Wvb, kb8, vTb, bk, bv,
      16384, 512, 512, 0, 0, 0);

  // fused attention: KVBLK=64 single-barrier pipeline, 2m x 4n QK split
  attn_fused<<<dim3(8, 32, 1), dim3(512), 0, stream>>>(qb8, kb8, vTb, out);
}

// Round 6
// 259.577 us; speedup vs baseline: 1.1108x; 1.1108x over previous
//
#include <hip/hip_runtime.h>

using u8  = unsigned char;
using u16 = unsigned short;
using u32 = unsigned int;
using s16x8 = __attribute__((ext_vector_type(8))) short;
using bf16x8 = __attribute__((ext_vector_type(8))) __bf16;
using f32x4 = __attribute__((ext_vector_type(4))) float;
using i32x4 = __attribute__((ext_vector_type(4))) int;
using i32x8 = __attribute__((ext_vector_type(8))) int;

__device__ inline u16 f2bf(float f) {
  u32 u = __float_as_uint(f);
  u = (u + 0x7FFFu + ((u >> 16) & 1u)) >> 16;
  return (u16)u;
}

// fp8 e4m3 (OCP) convert via HW pack instruction; take low byte
__device__ inline u8 f2fp8(float f) {
  return (u8)(__builtin_amdgcn_cvt_pk_fp8_f32(f, f, 0, false) & 0xFF);
}

__device__ inline f32x4 mfma16(s16x8 a, s16x8 b, f32x4 c) {
  return __builtin_amdgcn_mfma_f32_16x16x32_bf16(
      __builtin_bit_cast(bf16x8, a), __builtin_bit_cast(bf16x8, b), c, 0, 0, 0);
}

// MX fp8 MFMA, K=128, unit scales (e8m0 127 = 2^0): plain fp8 GEMM @2x bf16 rate
__device__ inline f32x4 mfma_fp8(i32x8 a, i32x8 b, f32x4 c) {
  return __builtin_amdgcn_mfma_scale_f32_16x16x128_f8f6f4(
      a, b, c, 0 /*A=fp8*/, 0 /*B=fp8*/, 0, 127, 0, 127);
}

// async global->LDS, 16B/lane; LDS dest = wave-uniform base + lane*16
__device__ inline void load_lds16(const void* g, void* l) {
  __builtin_amdgcn_global_load_lds(
      (const __attribute__((address_space(1))) void*)g,
      (__attribute__((address_space(3))) void*)l, 16, 0, 0);
}

// 8 fp32 -> s16x8 bf16 via HW pack (RNE, identical to f2bf)
__device__ inline s16x8 cvt8(f32x4 lo, f32x4 hi) {
  u32 w0, w1, w2, w3;
  asm("v_cvt_pk_bf16_f32 %0, %1, %2" : "=v"(w0) : "v"(lo[0]), "v"(lo[1]));
  asm("v_cvt_pk_bf16_f32 %0, %1, %2" : "=v"(w1) : "v"(lo[2]), "v"(lo[3]));
  asm("v_cvt_pk_bf16_f32 %0, %1, %2" : "=v"(w2) : "v"(hi[0]), "v"(hi[1]));
  asm("v_cvt_pk_bf16_f32 %0, %1, %2" : "=v"(w3) : "v"(hi[2]), "v"(hi[3]));
  i32x4 r;
  r[0] = (int)w0; r[1] = (int)w1; r[2] = (int)w2; r[3] = (int)w3;
  return __builtin_bit_cast(s16x8, r);
}

// ---------------------------------------------------------------------------
// weights cast (y=0..2) — only remaining cast pass (x-casts fused into GEMM)
__global__ __launch_bounds__(256) void cast_w3z(
    const float* __restrict__ a, const float* __restrict__ b,
    const float* __restrict__ c, u16* __restrict__ oa, u16* __restrict__ ob,
    u16* __restrict__ oc) {
  const float* in = blockIdx.y == 0 ? a : (blockIdx.y == 1 ? b : c);
  u16* out = blockIdx.y == 0 ? oa : (blockIdx.y == 1 ? ob : oc);
  int i = (blockIdx.x * 256 + threadIdx.x) * 4;
  float4 f = *(const float4*)(in + i);
  ushort4 o;
  o.x = f2bf(f.x); o.y = f2bf(f.y); o.z = f2bf(f.z); o.w = f2bf(f.w);
  *(ushort4*)(out + i) = o;
}

// ---------------------------------------------------------------------------
// Unified projection GEMM: C[m,n] = sum_k A[m,k]*B[n,k], M=16384, K=512.
// A = x1/x2 FP32 (cast fused: fp32 LDS staging + v_cvt_pk_bf16_f32 frags —
// removes the standalone x-cast kernel and its 235MB HBM round trip).
// B = W bf16 (pre-cast, tiny). 128x128 tile, BK=64, 4 waves.
// A staging: 16 granules(16B)/row, phys = g ^ (row&15)  (conflict-free per
// 8-lane window on both the staged write and the b128 frag reads).
// B staging: 8 granules/row, phys = g ^ (row&7) (validated gemm64 pattern).
// grid (12,128): col<4 -> q (A=x1,B=Wq -> fp8 qb8); col<8 -> k (x2,Wk ->
// fp8 kb8); else v (x2,Wv -> vT bf16 LDS-repack). XCD-chunked swizzle.
// ---------------------------------------------------------------------------
__global__ __launch_bounds__(256) void gemm_qkv(
    const float* __restrict__ x1, const float* __restrict__ x2,
    const u16* __restrict__ Wq, const u16* __restrict__ Wk,
    const u16* __restrict__ Wv, u8* __restrict__ qb8, u8* __restrict__ kb8,
    u16* __restrict__ vTb, const float* __restrict__ bq,
    const float* __restrict__ bk, const float* __restrict__ bv) {
  int flat = blockIdx.x + 12 * blockIdx.y;
  flat = (flat & 7) * 192 + (flat >> 3);  // XCD-chunked remap (1536 % 8 == 0)
  const int col = flat % 12;
  const int m0 = (flat / 12) * 128;

  const float* Ax; const u16* Bw; const float* bias; int n0w, mode;
  if (col < 4)      { Ax = x1; Bw = Wq; bias = bq; n0w = col * 128;       mode = 0; }
  else if (col < 8) { Ax = x2; Bw = Wk; bias = bk; n0w = (col - 4) * 128; mode = 1; }
  else              { Ax = x2; Bw = Wv; bias = bv; n0w = (col - 8) * 128; mode = 2; }

  const int tid = threadIdx.x;
  const int lane = tid & 63;
  const int wave = tid >> 6;
  const int wm = (wave >> 1) * 64;
  const int wn = (wave & 1) * 64;

  __shared__ float Asf[128 * 64];  // 32KB fp32 A tile, 16-gran XOR swizzle
  __shared__ u16 Bs[128 * 64];     // 16KB bf16 B tile, 8-gran XOR swizzle

  const int sr = lane >> 3;        // B: row within 8-row chunk
  const int gd = (lane & 7) ^ sr;  // B: swizzled source granule
  const int fr = lane & 15;
  const int fg = lane >> 4;        // 0..3

  f32x4 acc[4][4];
#pragma unroll
  for (int i = 0; i < 4; ++i)
#pragma unroll
    for (int j = 0; j < 4; ++j) acc[i][j] = 0.0f;

  for (int k0 = 0; k0 < 512; k0 += 64) {
    // A: 32 chunks of 4 rows (4 waves x 8); lane: row = l>>4, phys gran = l&15
#pragma unroll
    for (int it = 0; it < 8; ++it) {
      const int idx = wave * 8 + it;
      const int row = idx * 4 + (lane >> 4);
      const int gs = (lane & 15) ^ (row & 15);
      load_lds16(Ax + (size_t)(m0 + row) * 512 + k0 + gs * 4, &Asf[idx * 256]);
    }
    // B: 16 chunks of 8 rows (4 waves x 4)
#pragma unroll
    for (int it = 0; it < 4; ++it) {
      const int ch = wave * 4 + it;
      const int rowb = ch * 8 + sr;
      load_lds16(Bw + (size_t)(n0w + rowb) * 512 + k0 + gd * 8, &Bs[ch * 512]);
    }
    __syncthreads();
#pragma unroll
    for (int s = 0; s < 2; ++s) {
      s16x8 af[4], bfr[4];
#pragma unroll
      for (int i = 0; i < 4; ++i) {
        const int rowa = wm + i * 16 + fr;
        const float* Ar = &Asf[rowa * 64];
        const int g0 = 2 * (s * 4 + fg);
        f32x4 lo = *(const f32x4*)&Ar[(g0 ^ fr) * 4];
        f32x4 hi = *(const f32x4*)&Ar[((g0 + 1) ^ fr) * 4];
        af[i] = cvt8(lo, hi);
        const int slot = ((s * 4 + fg) ^ (fr & 7)) * 8;
        bfr[i] = *(const s16x8*)&Bs[(wn + i * 16 + fr) * 64 + slot];
      }
#pragma unroll
      for (int mi = 0; mi < 4; ++mi)
#pragma unroll
        for (int ni = 0; ni < 4; ++ni)
          acc[mi][ni] = mfma16(af[mi], bfr[ni], acc[mi][ni]);
    }
    __syncthreads();
  }

  // C/D layout: col = lane&15, row = (lane>>4)*4 + i
  const int er = fg * 4;
  const int ec = fr;

  if (mode != 2) {
    u8* Cb = (mode == 0) ? qb8 : kb8;
#pragma unroll
    for (int mi = 0; mi < 4; ++mi)
#pragma unroll
      for (int ni = 0; ni < 4; ++ni) {
        const int colg = n0w + wn + ni * 16 + ec;
        const float badd = bias[colg];
#pragma unroll
        for (int i = 0; i < 4; ++i) {
          const int row = m0 + wm + mi * 16 + er + i;
          Cb[(size_t)row * 512 + colg] = f2fp8(acc[mi][ni][i] + badd);
        }
      }
  } else {
    // v: transpose via LDS repack, bf16 out. Tb[c][r], stride 136 u16.
    u16* Tb = (u16*)Asf;  // 64*136 u16 = 17408 B, aliases dead staging
    const int batch = m0 >> 11;
    const int srow = m0 & 2047;
    u16* Cv = vTb + (size_t)batch * (512 * 2048);
#pragma unroll
    for (int h = 0; h < 2; ++h) {
      if ((wn >> 6) == h) {
#pragma unroll
        for (int mi = 0; mi < 4; ++mi)
#pragma unroll
          for (int ni = 0; ni < 4; ++ni) {
            const int c = ni * 16 + ec;
            const float badd = bias[n0w + wn + c];
#pragma unroll
            for (int i = 0; i < 4; ++i) {
              const int r = wm + mi * 16 + er + i;
              Tb[c * 136 + r] = f2bf(acc[mi][ni][i] + badd);
            }
          }
      }
      __syncthreads();
      const int d = tid >> 2;
      const int sc = (tid & 3) * 32;
      const int dglob = n0w + 64 * h + d;
#pragma unroll
      for (int j = 0; j < 4; ++j) {
        uint4 v = *(const uint4*)&Tb[d * 136 + sc + j * 8];
        *(uint4*)&Cv[(size_t)dglob * 2048 + srow + sc + j * 8] = v;
      }
      __syncthreads();
    }
  }
}

// ---------------------------------------------------------------------------
// Fused attention v6 = v4 structure (known 106us, no spill) + reg-neutral
// fixes: (a) P swizzle phi(r) = b2*4 + (b0^b3)*2 + b1 — conflict-free on
// BOTH the b16 P-writes (4 distinct slots over fg at fixed i, xor with the
// g-halves gives 8 distinct 16B regions = 32 banks) AND the b128 PV reads
// (8 distinct per 8-lane window); (b) s_setprio(1) around MFMA clusters.
// Register budget (8-wave block = 2 waves/SIMD => 256 unified cap):
// Qf 32 + Vr 32 + oacc 64(acc) + transients ~60 => no spill (tripwire:
// WRITE_SIZE must stay ~33 MB).
// Per tile t: QK(Ks[t&1]) -> exp -> Ps[t&1] -> barrier ->
//             stageK(t+2 -> Ks[t&1]) -> PV(Ps[t&1], Vr) -> loadV(t+1 -> Vr).
// QK split 4m x 2n (16q x 32kv per wave); PV pure d-split (64 d-cols/wave).
// ---------------------------------------------------------------------------
__global__ __launch_bounds__(512, 2) void attn_fused(
    const u8* __restrict__ q8, const u8* __restrict__ k8,
    const u16* __restrict__ vT, float* __restrict__ out) {
  const int batch = blockIdx.x;
  const int q0 = blockIdx.y * 64;
  const u8* qb = q8 + ((size_t)batch * 2048 + q0) * 512;
  const u8* kb = k8 + (size_t)batch * 2048 * 512;
  const u16* vb = vT + (size_t)batch * 512 * 2048;
  float* ob = out + ((size_t)batch * 2048 + q0) * 512;

  const int tid = threadIdx.x;
  const int lane = tid & 63;
  const int wave = tid >> 6;        // 0..7
  const int wm = (wave >> 1) * 16;  // QK q-row base (0/16/32/48)
  const int wn = (wave & 1) * 32;   // QK kv-col base (0/32)
  const int wd = wave * 64;         // PV d-col base
  const int sr = lane >> 3;
  const int gd = (lane & 7) ^ sr;   // staging swizzle (16B granules)
  const int fr = lane & 15;
  const int fg = lane >> 4;         // 0..3
  const int r7 = fr & 7;
  const int s0 = (2 * fg) ^ r7;     // LDS slot of k-lo granule (fp8 frags)
  const int s1 = s0 ^ 1;

  __shared__ u8 Ks[2][4][8192];   // dbuf x kc-chunk x (64 rows x 128B), swz
  __shared__ u16 Ps[2][64 * 64];  // dbuf P bf16, phi-XOR-swizzled granules

  // ---- Q fragments -> registers: 1 mi x 4 kc (rows wm+fr), 32 VGPRs
  i32x8 Qf[4];
#pragma unroll
  for (int kc = 0; kc < 4; ++kc) {
    const u8* p = qb + (size_t)(wm + fr) * 512 + kc * 128 + fg * 32;
    i32x4 lo = *(const i32x4*)p;
    i32x4 hi = *(const i32x4*)(p + 16);
    i32x8 q;
    q[0] = lo[0]; q[1] = lo[1]; q[2] = lo[2]; q[3] = lo[3];
    q[4] = hi[0]; q[5] = hi[1]; q[6] = hi[2]; q[7] = hi[3];
    Qf[kc] = q;
  }

  // 32KB K tile stage: 8 waves x 4 instrs
  auto stageK = [&](int kv0, int buf) {
#pragma unroll
    for (int it = 0; it < 4; ++it) {
      const int idx = wave * 4 + it;
      const int kc = idx >> 3, sub = idx & 7;
      load_lds16(kb + (size_t)(kv0 + sub * 8 + sr) * 512 + kc * 128 + gd * 16,
                 &Ks[buf][kc][sub * 1024]);
    }
  };
  // V frags for one tile -> 8 regs (ni4 x ks2), d = wd + ni*16 + fr
  s16x8 Vr[8];
  auto loadV = [&](int kv0) {
#pragma unroll
    for (int ks = 0; ks < 2; ++ks)
#pragma unroll
      for (int ni = 0; ni < 4; ++ni)
        Vr[ks * 4 + ni] = *(const s16x8*)&vb[(size_t)(wd + ni * 16 + fr) * 2048 +
                                             kv0 + ks * 32 + fg * 8];
  };

  f32x4 oacc[4][4];
#pragma unroll
  for (int i = 0; i < 4; ++i)
#pragma unroll
    for (int j = 0; j < 4; ++j) oacc[i][j] = 0.0f;
  float l_reg[4] = {0.0f, 0.0f, 0.0f, 0.0f};

  constexpr int NT = 32;

  auto tile = [&](int t, int psel) {
    // ---- QK^T: wave computes S[wm:wm+16)[wn:wn+32)
    f32x4 sacc[2];
    sacc[0] = 0.0f; sacc[1] = 0.0f;
#pragma unroll
    for (int kc = 0; kc < 4; ++kc) {
#pragma unroll
      for (int ni = 0; ni < 2; ++ni) {
        const u8* pb = &Ks[psel][kc][(wn + ni * 16 + fr) * 128];
        i32x4 blo = *(const i32x4*)(pb + s0 * 16);
        i32x4 bhi = *(const i32x4*)(pb + s1 * 16);
        i32x8 bK;
        bK[0] = blo[0]; bK[1] = blo[1]; bK[2] = blo[2]; bK[3] = blo[3];
        bK[4] = bhi[0]; bK[5] = bhi[1]; bK[6] = bhi[2]; bK[7] = bhi[3];
        __builtin_amdgcn_s_setprio(1);
        sacc[ni] = mfma_fp8(Qf[kc], bK, sacc[ni]);
        __builtin_amdgcn_s_setprio(0);
      }
    }
    // ---- P = exp(S/D) -> Ps[psel] (phi-swizzled), l partials.
    // C/D frag layout: col = wn + ni*16 + (lane&15), row = wm + (lane>>4)*4+i
    u16* Pd = &Ps[psel][0];
#pragma unroll
    for (int ni = 0; ni < 2; ++ni) {
      const int g = (wn >> 3) + ni * 2 + (fr >> 3);
      const int co = fr & 7;
#pragma unroll
      for (int i = 0; i < 4; ++i) {
        const int r = wm + fg * 4 + i;
        const int ph = ((r >> 2) & 1) * 4 + ((r ^ (r >> 3)) & 1) * 2 +
                       ((r >> 1) & 1);
        const float p = __expf(sacc[ni][i] * (1.0f / 512.0f));
        l_reg[i] += p;
        Pd[r * 64 + ((g ^ ph) << 3) + co] = f2bf(p);
      }
    }
    __syncthreads();  // P visible; K(t+1) (issued tile t-1) staged
    // ---- prefetch K two tiles ahead into the buffer QK just released
    if (t + 2 < NT) stageK((t + 2) * 64, psel);
    // ---- PV: O[0:64)[wd..wd+64) += P * V (V from regs, loaded tile t-1)
#pragma unroll
    for (int ks = 0; ks < 2; ++ks) {
      s16x8 pa[4];
#pragma unroll
      for (int mi = 0; mi < 4; ++mi) {
        const int r = mi * 16 + fr;
        const int ph = ((r >> 2) & 1) * 4 + ((r ^ (r >> 3)) & 1) * 2 +
                       ((r >> 1) & 1);
        pa[mi] = *(const s16x8*)&Pd[r * 64 + (((ks * 4 + fg) ^ ph) << 3)];
      }
      __builtin_amdgcn_s_setprio(1);
#pragma unroll
      for (int ni = 0; ni < 4; ++ni)
#pragma unroll
        for (int mi = 0; mi < 4; ++mi)
          oacc[mi][ni] = mfma16(pa[mi], Vr[ks * 4 + ni], oacc[mi][ni]);
      __builtin_amdgcn_s_setprio(0);
    }
    // ---- V for next tile into the SAME regs (WAR after PV reads, in order)
    if (t + 1 < NT) loadV((t + 1) * 64);
  };

  // prologue: K0+V0, drain, then K1 in flight (drains at tile-0 barrier)
  stageK(0, 0);
  loadV(0);
  __syncthreads();
  stageK(64, 1);

  for (int tt = 0; tt < NT; tt += 2) {
    tile(tt, 0);
    tile(tt + 1, 1);
  }

  // ---- l: shuffle-reduce over 16 lanes (kv-cols), partials into Ps scratch
  float* lsc = (float*)&Ps[0][0];  // [2 n-slices][64 rows]
  __syncthreads();
#pragma unroll
  for (int i = 0; i < 4; ++i) {
    float rs = l_reg[i];
    rs += __shfl_xor(rs, 1);
    rs += __shfl_xor(rs, 2);
    rs += __shfl_xor(rs, 4);
    rs += __shfl_xor(rs, 8);
    if (fr == 0) lsc[(wn >> 5) * 64 + wm + fg * 4 + i] = rs;
  }
  __syncthreads();

  // ---- normalize + store (fp32)
#pragma unroll
  for (int mi = 0; mi < 4; ++mi)
#pragma unroll
    for (int i = 0; i < 4; ++i) {
      const int r = mi * 16 + fg * 4 + i;
      const float l = lsc[r] + lsc[64 + r];
      const float li = __builtin_amdgcn_rcpf(l);
#pragma unroll
      for (int ni = 0; ni < 4; ++ni)
        ob[(size_t)r * 512 + wd + ni * 16 + fr] = oacc[mi][ni][i] * li;
    }
}

// ---------------------------------------------------------------------------
extern "C" void kernel_launch(void* const* d_in, const int* in_sizes, int n_in,
                              void* d_out, int out_size, void* d_ws, size_t ws_size,
                              hipStream_t stream) {
  constexpr int B = 8, S = 2048, D = 512;
  constexpr size_t MS = (size_t)B * S;  // 16384 token rows

  const float* x1 = (const float*)d_in[0];
  const float* x2 = (const float*)d_in[1];
  const float* Wq = (const float*)d_in[2];
  const float* bq = (const float*)d_in[3];
  const float* Wk = (const float*)d_in[4];
  const float* bk = (const float*)d_in[5];
  const float* Wv = (const float*)d_in[6];
  const float* bv = (const float*)d_in[7];
  float* out = (float*)d_out;

  // workspace layout (x1b/x2b slots retained but now unused — cast fused)
  u16* x1b = (u16*)d_ws;              // (unused)
  u16* x2b = x1b + MS * D;            // (unused)
  u16* Wqb = x2b + MS * D;            // D*D bf16
  u16* Wkb = Wqb + (size_t)D * D;
  u16* Wvb = Wkb + (size_t)D * D;
  u16* vTb = Wvb + (size_t)D * D;     // MS*D bf16  [B][D][S]
  u16* Sc  = vTb + MS * D;            // (unused)
  float* lbuf = (float*)(Sc + (size_t)B * S * S);  // (unused)
  u8* qb8 = (u8*)(lbuf + MS);         // MS*D fp8
  u8* kb8 = qb8 + MS * D;             // MS*D fp8

  dim3 blk(256);

  cast_w3z<<<dim3((D * D) / 1024, 3), blk, 0, stream>>>(
      Wq, Wk, Wv, Wqb, Wkb, Wvb);

  // unified q/k/v projections, fp32-A fused cast: 1536 blocks
  gemm_qkv<<<dim3(12, 128), blk, 0, stream>>>(
      x1, x2, Wqb, Wkb, Wvb, qb8, kb8, vTb, bq, bk, bv);

  // fused attention: KVBLK=64 single-barrier pipeline (v4 + swizzle/setprio)
  attn_fused<<<dim3(8, 32, 1), dim3(512), 0, stream>>>(qb8, kb8, vTb, out);
}

// Round 7
// 253.838 us; speedup vs baseline: 1.1359x; 1.0226x over previous
//
#include <hip/hip_runtime.h>

using u8  = unsigned char;
using u16 = unsigned short;
using u32 = unsigned int;
using s16x8 = __attribute__((ext_vector_type(8))) short;
using bf16x8 = __attribute__((ext_vector_type(8))) __bf16;
using f32x4 = __attribute__((ext_vector_type(4))) float;
using i32x4 = __attribute__((ext_vector_type(4))) int;
using i32x8 = __attribute__((ext_vector_type(8))) int;

__device__ inline u16 f2bf(float f) {
  u32 u = __float_as_uint(f);
  u = (u + 0x7FFFu + ((u >> 16) & 1u)) >> 16;
  return (u16)u;
}

// fp8 e4m3 (OCP) convert via HW pack instruction; take low byte
__device__ inline u8 f2fp8(float f) {
  return (u8)(__builtin_amdgcn_cvt_pk_fp8_f32(f, f, 0, false) & 0xFF);
}

__device__ inline f32x4 mfma16(s16x8 a, s16x8 b, f32x4 c) {
  return __builtin_amdgcn_mfma_f32_16x16x32_bf16(
      __builtin_bit_cast(bf16x8, a), __builtin_bit_cast(bf16x8, b), c, 0, 0, 0);
}

// MX fp8 MFMA, K=128, unit scales (e8m0 127 = 2^0): plain fp8 GEMM @2x bf16 rate
__device__ inline f32x4 mfma_fp8(i32x8 a, i32x8 b, f32x4 c) {
  return __builtin_amdgcn_mfma_scale_f32_16x16x128_f8f6f4(
      a, b, c, 0 /*A=fp8*/, 0 /*B=fp8*/, 0, 127, 0, 127);
}

// async global->LDS, 16B/lane; LDS dest = wave-uniform base + lane*16
__device__ inline void load_lds16(const void* g, void* l) {
  __builtin_amdgcn_global_load_lds(
      (const __attribute__((address_space(1))) void*)g,
      (__attribute__((address_space(3))) void*)l, 16, 0, 0);
}

// ---------------------------------------------------------------------------
// All fp32->bf16 casts in one launch. y=0: x1 (8192 blocks); y=1: x2;
// y=2: Wq/Wk/Wv in the first 768 blocks (256 each), rest exit.
// ---------------------------------------------------------------------------
__global__ __launch_bounds__(256) void cast_all(
    const float* __restrict__ x1, const float* __restrict__ x2,
    const float* __restrict__ wq, const float* __restrict__ wk,
    const float* __restrict__ wv, u16* __restrict__ o1, u16* __restrict__ o2,
    u16* __restrict__ oq, u16* __restrict__ ok, u16* __restrict__ ov) {
  const float* in;
  u16* out;
  int bx = blockIdx.x;
  if (blockIdx.y == 0) {
    in = x1; out = o1;
  } else if (blockIdx.y == 1) {
    in = x2; out = o2;
  } else {
    if (bx >= 768) return;
    const int w = bx >> 8;  // 0..2
    in = w == 0 ? wq : (w == 1 ? wk : wv);
    out = w == 0 ? oq : (w == 1 ? ok : ov);
    bx &= 255;
  }
  int i = (bx * 256 + threadIdx.x) * 4;
  float4 f = *(const float4*)(in + i);
  ushort4 o;
  o.x = f2bf(f.x); o.y = f2bf(f.y); o.z = f2bf(f.z); o.w = f2bf(f.w);
  *(ushort4*)(out + i) = o;
}

// ---------------------------------------------------------------------------
// Deep-pipelined projection GEMM: C[m,n] = sum_k A[m,k]*B[n,k], M=16384,
// K=512 (8 k-steps). gemm64's fragments/swizzle/epilogues kept verbatim,
// but A+B LDS double-buffered (64 KB -> 2 blocks/CU) and stage(k+1) issued
// BEFORE compute(k): the __syncthreads drain window for the staging DMA is
// the full 32-MFMA compute block (~1.2k cy) instead of zero — the round-0/6
// projection kernels were latency-bound on exactly this (161-215 TF).
// grid (12,128): col<4 -> q (x1,Wq -> fp8 qb8 +bias); col<8 -> k (x2,Wk ->
// fp8 kb8); else v (x2,Wv -> vT bf16 LDS repack). XCD-chunked swizzle:
// each XCD owns a 16-m-block panel (x1+x2 panels + W = ~3.5MB in its L2).
// ---------------------------------------------------------------------------
__global__ __launch_bounds__(256) void gemm_proj(
    const u16* __restrict__ x1b, const u16* __restrict__ x2b,
    const u16* __restrict__ Wqb, const u16* __restrict__ Wkb,
    const u16* __restrict__ Wvb, u8* __restrict__ qb8, u8* __restrict__ kb8,
    u16* __restrict__ vTb, const float* __restrict__ bq,
    const float* __restrict__ bk, const float* __restrict__ bv) {
  int flat = blockIdx.x + 12 * blockIdx.y;
  flat = (flat & 7) * 192 + (flat >> 3);  // XCD-chunked remap (1536 % 8 == 0)
  const int col = flat % 12;
  const int m0 = (flat / 12) * 128;

  const u16* Ax; const u16* Bw; const float* bias; int n0w, mode;
  if (col < 4)      { Ax = x1b; Bw = Wqb; bias = bq; n0w = col * 128;       mode = 0; }
  else if (col < 8) { Ax = x2b; Bw = Wkb; bias = bk; n0w = (col - 4) * 128; mode = 1; }
  else              { Ax = x2b; Bw = Wvb; bias = bv; n0w = (col - 8) * 128; mode = 2; }

  const int tid = threadIdx.x;
  const int lane = tid & 63;
  const int wave = tid >> 6;
  const int wm = (wave >> 1) * 64;
  const int wn = (wave & 1) * 64;

  __shared__ u16 As_[2][128 * 64];  // 2 x 16KB
  __shared__ u16 Bs_[2][128 * 64];  // 2 x 16KB

  const int sr = lane >> 3;        // row within 8-row chunk
  const int gd = (lane & 7) ^ sr;  // swizzled source granule (16B units)
  const int fr = lane & 15;
  const int fg = lane >> 4;        // 0..3

  auto stage = [&](int k0, int b) {
#pragma unroll
    for (int it = 0; it < 4; ++it) {
      const int ch = wave * 4 + it;
      const int row = ch * 8 + sr;
      load_lds16(Ax + (size_t)(m0 + row) * 512 + k0 + gd * 8, &As_[b][ch * 512]);
      load_lds16(Bw + (size_t)(n0w + row) * 512 + k0 + gd * 8, &Bs_[b][ch * 512]);
    }
  };

  f32x4 acc[4][4];
#pragma unroll
  for (int i = 0; i < 4; ++i)
#pragma unroll
    for (int j = 0; j < 4; ++j) acc[i][j] = 0.0f;

  stage(0, 0);
  __syncthreads();  // drain: buf0 ready

  for (int ks = 0; ks < 8; ++ks) {
    const int b = ks & 1;
    if (ks < 7) stage((ks + 1) * 64, b ^ 1);  // overlaps compute below
#pragma unroll
    for (int s = 0; s < 2; ++s) {
      const int slot = ((s * 4 + fg) ^ (fr & 7)) * 8;
      s16x8 af[4], bfr[4];
#pragma unroll
      for (int i = 0; i < 4; ++i) {
        af[i]  = *(const s16x8*)&As_[b][(wm + i * 16 + fr) * 64 + slot];
        bfr[i] = *(const s16x8*)&Bs_[b][(wn + i * 16 + fr) * 64 + slot];
      }
      __builtin_amdgcn_s_setprio(1);
#pragma unroll
      for (int mi = 0; mi < 4; ++mi)
#pragma unroll
        for (int ni = 0; ni < 4; ++ni)
          acc[mi][ni] = mfma16(af[mi], bfr[ni], acc[mi][ni]);
      __builtin_amdgcn_s_setprio(0);
    }
    __syncthreads();  // stage(ks+1) drained; all reads of buf b done
  }

  // C/D layout: col = lane&15, row = (lane>>4)*4 + i
  const int er = fg * 4;
  const int ec = fr;

  if (mode != 2) {
    u8* Cb = (mode == 0) ? qb8 : kb8;
#pragma unroll
    for (int mi = 0; mi < 4; ++mi)
#pragma unroll
      for (int ni = 0; ni < 4; ++ni) {
        const int colg = n0w + wn + ni * 16 + ec;
        const float badd = bias[colg];
#pragma unroll
        for (int i = 0; i < 4; ++i) {
          const int row = m0 + wm + mi * 16 + er + i;
          Cb[(size_t)row * 512 + colg] = f2fp8(acc[mi][ni][i] + badd);
        }
      }
  } else {
    // v: transpose via LDS repack, bf16 out. Tb[c][r], stride 136 u16.
    u16* Tb = &As_[0][0];  // 17408 B, aliases dead staging
    const int batch = m0 >> 11;
    const int srow = m0 & 2047;
    u16* Cv = vTb + (size_t)batch * (512 * 2048);
#pragma unroll
    for (int h = 0; h < 2; ++h) {
      if ((wn >> 6) == h) {
#pragma unroll
        for (int mi = 0; mi < 4; ++mi)
#pragma unroll
          for (int ni = 0; ni < 4; ++ni) {
            const int c = ni * 16 + ec;
            const float badd = bias[n0w + wn + c];
#pragma unroll
            for (int i = 0; i < 4; ++i) {
              const int r = wm + mi * 16 + er + i;
              Tb[c * 136 + r] = f2bf(acc[mi][ni][i] + badd);
            }
          }
      }
      __syncthreads();
      const int d = tid >> 2;
      const int sc = (tid & 3) * 32;
      const int dglob = n0w + 64 * h + d;
#pragma unroll
      for (int j = 0; j < 4; ++j) {
        uint4 v = *(const uint4*)&Tb[d * 136 + sc + j * 8];
        *(uint4*)&Cv[(size_t)dglob * 2048 + srow + sc + j * 8] = v;
      }
      __syncthreads();
    }
  }
}

// ---------------------------------------------------------------------------
// Fused attention v7 = v6 with setprio moved to cluster level (per-mfma
// wrapping in v6 was 20 SALU pairs/tile with no benefit). Structure
// unchanged (107us, no spill, latency-bound at 2 waves/SIMD — parked).
// Per tile t: QK(Ks[t&1]) -> exp -> Ps[t&1] -> barrier ->
//             stageK(t+2 -> Ks[t&1]) -> PV(Ps[t&1], Vr) -> loadV(t+1 -> Vr).
// QK split 4m x 2n (16q x 32kv per wave); PV pure d-split (64 d-cols/wave).
// ---------------------------------------------------------------------------
__global__ __launch_bounds__(512, 2) void attn_fused(
    const u8* __restrict__ q8, const u8* __restrict__ k8,
    const u16* __restrict__ vT, float* __restrict__ out) {
  const int batch = blockIdx.x;
  const int q0 = blockIdx.y * 64;
  const u8* qb = q8 + ((size_t)batch * 2048 + q0) * 512;
  const u8* kb = k8 + (size_t)batch * 2048 * 512;
  const u16* vb = vT + (size_t)batch * 512 * 2048;
  float* ob = out + ((size_t)batch * 2048 + q0) * 512;

  const int tid = threadIdx.x;
  const int lane = tid & 63;
  const int wave = tid >> 6;        // 0..7
  const int wm = (wave >> 1) * 16;  // QK q-row base (0/16/32/48)
  const int wn = (wave & 1) * 32;   // QK kv-col base (0/32)
  const int wd = wave * 64;         // PV d-col base
  const int sr = lane >> 3;
  const int gd = (lane & 7) ^ sr;   // staging swizzle (16B granules)
  const int fr = lane & 15;
  const int fg = lane >> 4;         // 0..3
  const int r7 = fr & 7;
  const int s0 = (2 * fg) ^ r7;     // LDS slot of k-lo granule (fp8 frags)
  const int s1 = s0 ^ 1;

  __shared__ u8 Ks[2][4][8192];   // dbuf x kc-chunk x (64 rows x 128B), swz
  __shared__ u16 Ps[2][64 * 64];  // dbuf P bf16, phi-XOR-swizzled granules

  // ---- Q fragments -> registers: 1 mi x 4 kc (rows wm+fr), 32 VGPRs
  i32x8 Qf[4];
#pragma unroll
  for (int kc = 0; kc < 4; ++kc) {
    const u8* p = qb + (size_t)(wm + fr) * 512 + kc * 128 + fg * 32;
    i32x4 lo = *(const i32x4*)p;
    i32x4 hi = *(const i32x4*)(p + 16);
    i32x8 q;
    q[0] = lo[0]; q[1] = lo[1]; q[2] = lo[2]; q[3] = lo[3];
    q[4] = hi[0]; q[5] = hi[1]; q[6] = hi[2]; q[7] = hi[3];
    Qf[kc] = q;
  }

  // 32KB K tile stage: 8 waves x 4 instrs
  auto stageK = [&](int kv0, int buf) {
#pragma unroll
    for (int it = 0; it < 4; ++it) {
      const int idx = wave * 4 + it;
      const int kc = idx >> 3, sub = idx & 7;
      load_lds16(kb + (size_t)(kv0 + sub * 8 + sr) * 512 + kc * 128 + gd * 16,
                 &Ks[buf][kc][sub * 1024]);
    }
  };
  // V frags for one tile -> 8 regs (ni4 x ks2), d = wd + ni*16 + fr
  s16x8 Vr[8];
  auto loadV = [&](int kv0) {
#pragma unroll
    for (int ks = 0; ks < 2; ++ks)
#pragma unroll
      for (int ni = 0; ni < 4; ++ni)
        Vr[ks * 4 + ni] = *(const s16x8*)&vb[(size_t)(wd + ni * 16 + fr) * 2048 +
                                             kv0 + ks * 32 + fg * 8];
  };

  f32x4 oacc[4][4];
#pragma unroll
  for (int i = 0; i < 4; ++i)
#pragma unroll
    for (int j = 0; j < 4; ++j) oacc[i][j] = 0.0f;
  float l_reg[4] = {0.0f, 0.0f, 0.0f, 0.0f};

  constexpr int NT = 32;

  auto tile = [&](int t, int psel) {
    // ---- QK^T: wave computes S[wm:wm+16)[wn:wn+32)
    f32x4 sacc[2];
    sacc[0] = 0.0f; sacc[1] = 0.0f;
    __builtin_amdgcn_s_setprio(1);
#pragma unroll
    for (int kc = 0; kc < 4; ++kc) {
#pragma unroll
      for (int ni = 0; ni < 2; ++ni) {
        const u8* pb = &Ks[psel][kc][(wn + ni * 16 + fr) * 128];
        i32x4 blo = *(const i32x4*)(pb + s0 * 16);
        i32x4 bhi = *(const i32x4*)(pb + s1 * 16);
        i32x8 bK;
        bK[0] = blo[0]; bK[1] = blo[1]; bK[2] = blo[2]; bK[3] = blo[3];
        bK[4] = bhi[0]; bK[5] = bhi[1]; bK[6] = bhi[2]; bK[7] = bhi[3];
        sacc[ni] = mfma_fp8(Qf[kc], bK, sacc[ni]);
      }
    }
    __builtin_amdgcn_s_setprio(0);
    // ---- P = exp(S/D) -> Ps[psel] (phi-swizzled), l partials.
    // C/D frag layout: col = wn + ni*16 + (lane&15), row = wm + (lane>>4)*4+i
    u16* Pd = &Ps[psel][0];
#pragma unroll
    for (int ni = 0; ni < 2; ++ni) {
      const int g = (wn >> 3) + ni * 2 + (fr >> 3);
      const int co = fr & 7;
#pragma unroll
      for (int i = 0; i < 4; ++i) {
        const int r = wm + fg * 4 + i;
        const int ph = ((r >> 2) & 1) * 4 + ((r ^ (r >> 3)) & 1) * 2 +
                       ((r >> 1) & 1);
        const float p = __expf(sacc[ni][i] * (1.0f / 512.0f));
        l_reg[i] += p;
        Pd[r * 64 + ((g ^ ph) << 3) + co] = f2bf(p);
      }
    }
    __syncthreads();  // P visible; K(t+1) (issued tile t-1) staged
    // ---- prefetch K two tiles ahead into the buffer QK just released
    if (t + 2 < NT) stageK((t + 2) * 64, psel);
    // ---- PV: O[0:64)[wd..wd+64) += P * V (V from regs, loaded tile t-1)
#pragma unroll
    for (int ks = 0; ks < 2; ++ks) {
      s16x8 pa[4];
#pragma unroll
      for (int mi = 0; mi < 4; ++mi) {
        const int r = mi * 16 + fr;
        const int ph = ((r >> 2) & 1) * 4 + ((r ^ (r >> 3)) & 1) * 2 +
                       ((r >> 1) & 1);
        pa[mi] = *(const s16x8*)&Pd[r * 64 + (((ks * 4 + fg) ^ ph) << 3)];
      }
      __builtin_amdgcn_s_setprio(1);
#pragma unroll
      for (int ni = 0; ni < 4; ++ni)
#pragma unroll
        for (int mi = 0; mi < 4; ++mi)
          oacc[mi][ni] = mfma16(pa[mi], Vr[ks * 4 + ni], oacc[mi][ni]);
      __builtin_amdgcn_s_setprio(0);
    }
    // ---- V for next tile into the SAME regs (WAR after PV reads, in order)
    if (t + 1 < NT) loadV((t + 1) * 64);
  };

  // prologue: K0+V0, drain, then K1 in flight (drains at tile-0 barrier)
  stageK(0, 0);
  loadV(0);
  __syncthreads();
  stageK(64, 1);

  for (int tt = 0; tt < NT; tt += 2) {
    tile(tt, 0);
    tile(tt + 1, 1);
  }

  // ---- l: shuffle-reduce over 16 lanes (kv-cols), partials into Ps scratch
  float* lsc = (float*)&Ps[0][0];  // [2 n-slices][64 rows]
  __syncthreads();
#pragma unroll
  for (int i = 0; i < 4; ++i) {
    float rs = l_reg[i];
    rs += __shfl_xor(rs, 1);
    rs += __shfl_xor(rs, 2);
    rs += __shfl_xor(rs, 4);
    rs += __shfl_xor(rs, 8);
    if (fr == 0) lsc[(wn >> 5) * 64 + wm + fg * 4 + i] = rs;
  }
  __syncthreads();

  // ---- normalize + store (fp32)
#pragma unroll
  for (int mi = 0; mi < 4; ++mi)
#pragma unroll
    for (int i = 0; i < 4; ++i) {
      const int r = mi * 16 + fg * 4 + i;
      const float l = lsc[r] + lsc[64 + r];
      const float li = __builtin_amdgcn_rcpf(l);
#pragma unroll
      for (int ni = 0; ni < 4; ++ni)
        ob[(size_t)r * 512 + wd + ni * 16 + fr] = oacc[mi][ni][i] * li;
    }
}

// ---------------------------------------------------------------------------
extern "C" void kernel_launch(void* const* d_in, const int* in_sizes, int n_in,
                              void* d_out, int out_size, void* d_ws, size_t ws_size,
                              hipStream_t stream) {
  constexpr int B = 8, S = 2048, D = 512;
  constexpr size_t MS = (size_t)B * S;  // 16384 token rows

  const float* x1 = (const float*)d_in[0];
  const float* x2 = (const float*)d_in[1];
  const float* Wq = (const float*)d_in[2];
  const float* bq = (const float*)d_in[3];
  const float* Wk = (const float*)d_in[4];
  const float* bk = (const float*)d_in[5];
  const float* Wv = (const float*)d_in[6];
  const float* bv = (const float*)d_in[7];
  float* out = (float*)d_out;

  // workspace layout
  u16* x1b = (u16*)d_ws;              // MS*D bf16
  u16* x2b = x1b + MS * D;            // MS*D bf16
  u16* Wqb = x2b + MS * D;            // D*D bf16
  u16* Wkb = Wqb + (size_t)D * D;
  u16* Wvb = Wkb + (size_t)D * D;
  u16* vTb = Wvb + (size_t)D * D;     // MS*D bf16  [B][D][S]
  u16* Sc  = vTb + MS * D;            // (unused)
  float* lbuf = (float*)(Sc + (size_t)B * S * S);  // (unused)
  u8* qb8 = (u8*)(lbuf + MS);         // MS*D fp8
  u8* kb8 = qb8 + MS * D;             // MS*D fp8

  dim3 blk(256);

  // all casts, one launch: y=0 x1, y=1 x2, y=2 (first 768 blocks) weights
  cast_all<<<dim3((MS * D) / 1024, 3), blk, 0, stream>>>(
      x1, x2, Wq, Wk, Wv, x1b, x2b, Wqb, Wkb, Wvb);

  // unified q/k/v projections, A+B double-buffered pipeline: 1536 blocks
  gemm_proj<<<dim3(12, 128), blk, 0, stream>>>(
      x1b, x2b, Wqb, Wkb, Wvb, qb8, kb8, vTb, bq, bk, bv);

  // fused attention: KVBLK=64 single-barrier pipeline
  attn_fused<<<dim3(8, 32, 1), dim3(512), 0, stream>>>(qb8, kb8, vTb, out);
}